// Round 1
// baseline (1263.180 us; speedup 1.0000x reference)
//
#include <hip/hip_runtime.h>
#include <math.h>

// CrossEntropyWithPerDomainLoss on MI355X (gfx950)
// B=4, S=2048, V=32000, D=8. Memory-bound: single pass over 1.048 GB of logits.
// R3: one WAVE per token row (was one block/row). V4 = 8000 = 64 lanes x 5 chains
// x 25 iters exactly: uniform loop, no divergent tail, no __syncthreads, no LDS
// combine. Explicit prefetch keeps 10 loads (10 KB) in flight per wave; the
// uniform label/label-logit loads are issued at wave start and consumed at the
// end. Prev structure kept only one 4-load iteration outstanding and spent
// ~40% of each short block's life in prologue latency + serial tail + epilogue.

#define NDOM 8

typedef float v4f __attribute__((ext_vector_type(4)));
typedef int   v4i __attribute__((ext_vector_type(4)));

// ---------------- Kernel 1: per-token online-softmax CE loss ----------------
// One wave per row; 4 independent waves per 256-thread block.
// Assumes (V/4) % 64 == 0 (V = 32000 -> 125 v4f chunks per lane).
__global__ __launch_bounds__(256) void ce_rowwave_kernel(
    const float* __restrict__ logits,   // [T, V]
    const int* __restrict__ labels,     // [T]
    float* __restrict__ per_token_loss, // [T] (workspace)
    int V)
{
    const int lane = threadIdx.x & 63;
    const int row  = (blockIdx.x << 2) + (threadIdx.x >> 6);

    const float L2E = 1.4426950408889634f;  // log2(e)
    const float LN2 = 0.6931471805599453f;

    const size_t rowbase = (size_t)row * (size_t)V;
    const v4f* rp = reinterpret_cast<const v4f*>(logits + rowbase);
    const int V4     = V >> 2;
    const int nchunk = V4 >> 6;   // per-lane v4f chunks (125 at V=32000)
    const int nfull  = nchunk / 5;

    // Uniform loads issued early (scalarizable): consumed only at the end,
    // latency fully hidden under the 25-iteration main loop.
    const int   lab = labels[row];
    const float xl  = logits[rowbase + (size_t)lab];

    // 5 independent online-softmax accumulators.
    float m[5]  = {-INFINITY, -INFINITY, -INFINITY, -INFINITY, -INFINITY};
    float mL[5] = {0.f, 0.f, 0.f, 0.f, 0.f};  // m * log2(e), refreshed on max update
    float s[5]  = {0.f, 0.f, 0.f, 0.f, 0.f};  // sum of e^(x - m)

    auto upd = [&](int k, v4f v) {
        float m4 = fmaxf(fmaxf(v.x, v.y), fmaxf(v.z, v.w));
        if (m4 > m[k]) {                       // rare after warm-up
            s[k] *= exp2f((m[k] - m4) * L2E);  // exp2(-inf)=0 on first iter, s==0 anyway
            m[k] = m4;
            mL[k] = m4 * L2E;
        }
        // e^(x - m) == 2^(x*log2e - m*log2e): one FMA + native v_exp_f32 each
        s[k] += exp2f(fmaf(v.x, L2E, -mL[k])) + exp2f(fmaf(v.y, L2E, -mL[k]))
              + exp2f(fmaf(v.z, L2E, -mL[k])) + exp2f(fmaf(v.w, L2E, -mL[k]));
    };

    // Software-pipelined main loop: chain c, iter i reads chunk k = 5*i + c.
    // Wave footprint per iter: 5 contiguous 1-KB groups (coalesced 16 B/lane).
    v4f cur[5], nxt[5];
    #pragma unroll
    for (int c = 0; c < 5; ++c)
        cur[c] = __builtin_nontemporal_load(rp + (c << 6) + lane);

    for (int i = 1; i < nfull; ++i) {
        const int base = i * 320 + lane;       // 5*64 elements per iteration
        #pragma unroll
        for (int c = 0; c < 5; ++c)            // issue next iteration's loads first:
            nxt[c] = __builtin_nontemporal_load(rp + base + (c << 6));
        #pragma unroll
        for (int c = 0; c < 5; ++c)            // consume current (vmcnt(5) wait)
            upd(c, cur[c]);
        #pragma unroll
        for (int c = 0; c < 5; ++c)
            cur[c] = nxt[c];
    }
    #pragma unroll
    for (int c = 0; c < 5; ++c)
        upd(c, cur[c]);

    for (int k = nfull * 5; k < nchunk; ++k)   // generic remainder (empty at V=32000)
        upd(0, __builtin_nontemporal_load(rp + (k << 6) + lane));

    // merge the 5 per-thread accumulators
    float M = m[0], S = s[0];
    #pragma unroll
    for (int k = 1; k < 5; ++k) {
        float mn = fmaxf(M, m[k]);
        S = S * exp2f((M - mn) * L2E) + s[k] * exp2f((m[k] - mn) * L2E);
        M = mn;
    }

    // 64-lane butterfly reduce of the (M, S) pair — whole-wave, no LDS needed
    #pragma unroll
    for (int off = 1; off < 64; off <<= 1) {
        float mo = __shfl_xor(M, off, 64);
        float so = __shfl_xor(S, off, 64);
        float mn = fmaxf(M, mo);
        S = S * exp2f((M - mn) * L2E) + so * exp2f((mo - mn) * L2E);
        M = mn;
    }

    if (lane == 0)
        per_token_loss[row] = M + log2f(S) * LN2 - xl;  // lse - logit[label]
}

// ---------------- Kernel 2: reductions + per-domain finalize ----------------
// Single 256-thread block, vectorized. T = 8192 floats — negligible cost.
__global__ __launch_bounds__(256) void ce_finalize_kernel(
    const float* __restrict__ per_token_loss, // [T]
    const int* __restrict__ mask,             // [T] (bool as int32)
    const int* __restrict__ domain_idxs,      // [B]
    float* __restrict__ out,                  // [1 + NDOM + NDOM]
    int T, int B, int S)
{
    const int t = threadIdx.x;
    const v4f* pl4 = reinterpret_cast<const v4f*>(per_token_loss);
    const v4i* mk4 = reinterpret_cast<const v4i*>(mask);
    const int T4 = T >> 2;
    const int S4 = S >> 2;

    float tot = 0.0f, cnt = 0.0f;
    float samp[4] = {0.f, 0.f, 0.f, 0.f};  // B == 4

    for (int i = t; i < T4; i += 256) {   // 8 iterations
        v4f l = pl4[i];
        v4i mk = mk4[i];
        tot += (mk.x ? l.x : 0.f) + (mk.y ? l.y : 0.f)
             + (mk.z ? l.z : 0.f) + (mk.w ? l.w : 0.f);
        cnt += (mk.x ? 1.f : 0.f) + (mk.y ? 1.f : 0.f)
             + (mk.z ? 1.f : 0.f) + (mk.w ? 1.f : 0.f);
        samp[i / S4] += l.x + l.y + l.z + l.w;  // per-sample sums are UNMASKED
    }

    __shared__ float red[6][256];
    red[0][t] = tot;     red[1][t] = cnt;
    red[2][t] = samp[0]; red[3][t] = samp[1];
    red[4][t] = samp[2]; red[5][t] = samp[3];
    __syncthreads();

    for (int off = 128; off > 0; off >>= 1) {
        if (t < off) {
            #pragma unroll
            for (int k = 0; k < 6; k++) red[k][t] += red[k][t + off];
        }
        __syncthreads();
    }

    if (t == 0) {
        out[0] = red[0][0] / red[1][0];  // ce_loss (masked mean)

        float dl[NDOM];
        int sc[NDOM];
        #pragma unroll
        for (int d = 0; d < NDOM; d++) { dl[d] = 0.0f; sc[d] = 0; }
        for (int b = 0; b < B; b++) {
            int d = domain_idxs[b];
            dl[d] += red[2 + b][0];
            sc[d] += 1;
        }
        #pragma unroll
        for (int d = 0; d < NDOM; d++) {
            float denom = (float)sc[d] * (float)S;
            out[1 + d]        = (denom > 0.0f) ? (dl[d] / denom) : 0.0f;
            out[1 + NDOM + d] = (float)sc[d];
        }
    }
}

extern "C" void kernel_launch(void* const* d_in, const int* in_sizes, int n_in,
                              void* d_out, int out_size, void* d_ws, size_t ws_size,
                              hipStream_t stream) {
    const float* logits     = (const float*)d_in[0];
    const int* labels       = (const int*)d_in[1];
    const int* mask         = (const int*)d_in[2];
    const int* domain_idxs  = (const int*)d_in[3];
    float* out              = (float*)d_out;

    const int T = in_sizes[1];                 // B*S = 8192
    const int V = in_sizes[0] / T;             // 32000
    const int B = in_sizes[3];                 // 4
    const int S = T / B;                       // 2048

    float* per_token_loss = (float*)d_ws;      // T floats = 32 KiB

    // one wave per row: 4 rows per 256-thread block
    ce_rowwave_kernel<<<T >> 2, 256, 0, stream>>>(logits, labels, per_token_loss, V);
    ce_finalize_kernel<<<1, 256, 0, stream>>>(per_token_loss, mask, domain_idxs,
                                              out, T, B, S);
}